// Round 6
// baseline (163.245 us; speedup 1.0000x reference)
//
#include <hip/hip_runtime.h>
#include <math.h>

// SIREN forward: coords [N,3] -> first(3->5,sin) -> 256 x hidden(5->5,sin) -> final(5->1)
// Output layout: d_out[0..N) = net output, d_out[N..4N) = coords passthrough.
//
// Round 6:
//  - Keep deg-9 poly sin (R5 showed it is issue-bound as modeled, ~2cyc/instr).
//  - P=2 points/thread: R5's loss vs prediction was GROWN IDLE at 2 waves/SIMD
//    (launch-limited). Per-SIMD issue totals are ~equal for P=1/2/4, so halve
//    P to double waves/SIMD (4) for dep-chain + s_load latency hiding.
//  - #pragma unroll 4 for a deeper scalar-prefetch window.
//  - Weights pre-scaled by 30/(2pi) in d_ws ([256][32] f32): sin in revolution
//    units, rndne range reduction exact, |z| <= ~7.6 rev.
//  - Uniform control flow; weight reads scalarize to s_load (K$/L2).

#define SIREN_HID 5
#define SIREN_NLAYERS 256
// 30 / (2*pi)
#define SIREN_REV 4.774648292756860f

// sin(2*pi*z) via degree-9 odd Chebyshev-truncated poly after exact range
// reduction. 8 full-rate VALU ops (rndne, sub, mul, 4x fma, mul).
__device__ __forceinline__ float sinrev(float z) {
    float k  = __builtin_rintf(z);         // v_rndne_f32
    float r  = z - k;                      // exact, r in [-0.5, 0.5]
    float r2 = r * r;
    float p  = fmaf(32.768f,       r2, -74.4734720f);
    p        = fmaf(p,             r2,  81.3648896f);
    p        = fmaf(p,             r2, -41.3310592f);
    p        = fmaf(p,             r2,   6.2830548f);
    return p * r;
}

// ---------------- prep: scale weights into revolution units ----------------
// d_ws layout (floats):
//   [0 .. 8192)        hidden layers: layer l at l*32: w[0..24], b[25..29], pad
//   [8192 .. 8207)     first layer W (5x3, row-major), scaled
//   [8207 .. 8212)     first layer b, scaled
__global__ __launch_bounds__(256)
void siren_prep(const float* __restrict__ Wf, const float* __restrict__ bf,
                const float* __restrict__ Wh, const float* __restrict__ bh,
                float* __restrict__ ws)
{
    int t = blockIdx.x * blockDim.x + threadIdx.x;
    const int total = SIREN_NLAYERS * 32;
    for (int idx = t; idx < total; idx += gridDim.x * blockDim.x) {
        int l = idx >> 5;
        int k = idx & 31;
        float v = 0.0f;
        if (k < 25)      v = Wh[l * 25 + k] * SIREN_REV;
        else if (k < 30) v = bh[l * 5 + (k - 25)] * SIREN_REV;
        ws[idx] = v;
    }
    if (t < 15) ws[total + t]      = Wf[t] * SIREN_REV;
    if (t < 5)  ws[total + 15 + t] = bf[t] * SIREN_REV;
}

// ---------------- main: 2 points per thread, poly sin ----------------
__global__ __launch_bounds__(256)
void siren_fwd6(const float* __restrict__ coords,
                const float* __restrict__ lw,    // [256][32] scaled hidden w/b
                const float* __restrict__ fw,    // [20] scaled first w(15)+b(5)
                const float* __restrict__ Wfin,  // [1][5] (unscaled)
                const float* __restrict__ bfin,  // [1]
                float* __restrict__ out, int N)
{
    int i = blockIdx.x * blockDim.x + threadIdx.x;
    const int M = N >> 1;                 // pairs
    i = (i < M) ? i : (M - 1);            // uniform clamp, no divergent return

    // two adjacent points: 24B contiguous (float4 + float2)
    const float* cp = coords + 6 * i;
    float4 q0 = *(const float4*)(cp);      // a0 a1 a2 b0
    float2 q1 = *(const float2*)(cp + 4);  // b1 b2
    float a0 = q0.x, a1 = q0.y, a2 = q0.z;
    float b0 = q0.w, b1 = q1.x, b2 = q1.y;

    // first layer (revolution units): h_j = sin_rev(c . w[j,:] + b[j])
    float ha0, ha1, ha2, ha3, ha4;
    float hb0, hb1, hb2, hb3, hb4;
    {
        float za0 = fmaf(a2, fw[ 2], fmaf(a1, fw[ 1], fmaf(a0, fw[ 0], fw[15])));
        float zb0 = fmaf(b2, fw[ 2], fmaf(b1, fw[ 1], fmaf(b0, fw[ 0], fw[15])));
        float za1 = fmaf(a2, fw[ 5], fmaf(a1, fw[ 4], fmaf(a0, fw[ 3], fw[16])));
        float zb1 = fmaf(b2, fw[ 5], fmaf(b1, fw[ 4], fmaf(b0, fw[ 3], fw[16])));
        float za2 = fmaf(a2, fw[ 8], fmaf(a1, fw[ 7], fmaf(a0, fw[ 6], fw[17])));
        float zb2 = fmaf(b2, fw[ 8], fmaf(b1, fw[ 7], fmaf(b0, fw[ 6], fw[17])));
        float za3 = fmaf(a2, fw[11], fmaf(a1, fw[10], fmaf(a0, fw[ 9], fw[18])));
        float zb3 = fmaf(b2, fw[11], fmaf(b1, fw[10], fmaf(b0, fw[ 9], fw[18])));
        float za4 = fmaf(a2, fw[14], fmaf(a1, fw[13], fmaf(a0, fw[12], fw[19])));
        float zb4 = fmaf(b2, fw[14], fmaf(b1, fw[13], fmaf(b0, fw[12], fw[19])));
        ha0 = sinrev(za0); hb0 = sinrev(zb0);
        ha1 = sinrev(za1); hb1 = sinrev(zb1);
        ha2 = sinrev(za2); hb2 = sinrev(zb2);
        ha3 = sinrev(za3); hb3 = sinrev(zb3);
        ha4 = sinrev(za4); hb4 = sinrev(zb4);
    }

    // 256 hidden layers (revolution units)
#pragma unroll 4
    for (int l = 0; l < SIREN_NLAYERS; ++l) {
        const float* w = lw + l * 32;
        float p0 = w[25], p1 = w[26], p2 = w[27], p3 = w[28], p4 = w[29];
        float za0 = fmaf(ha4, w[ 4], fmaf(ha3, w[ 3], fmaf(ha2, w[ 2], fmaf(ha1, w[ 1], fmaf(ha0, w[ 0], p0)))));
        float zb0 = fmaf(hb4, w[ 4], fmaf(hb3, w[ 3], fmaf(hb2, w[ 2], fmaf(hb1, w[ 1], fmaf(hb0, w[ 0], p0)))));
        float za1 = fmaf(ha4, w[ 9], fmaf(ha3, w[ 8], fmaf(ha2, w[ 7], fmaf(ha1, w[ 6], fmaf(ha0, w[ 5], p1)))));
        float zb1 = fmaf(hb4, w[ 9], fmaf(hb3, w[ 8], fmaf(hb2, w[ 7], fmaf(hb1, w[ 6], fmaf(hb0, w[ 5], p1)))));
        float za2 = fmaf(ha4, w[14], fmaf(ha3, w[13], fmaf(ha2, w[12], fmaf(ha1, w[11], fmaf(ha0, w[10], p2)))));
        float zb2 = fmaf(hb4, w[14], fmaf(hb3, w[13], fmaf(hb2, w[12], fmaf(hb1, w[11], fmaf(hb0, w[10], p2)))));
        float za3 = fmaf(ha4, w[19], fmaf(ha3, w[18], fmaf(ha2, w[17], fmaf(ha1, w[16], fmaf(ha0, w[15], p3)))));
        float zb3 = fmaf(hb4, w[19], fmaf(hb3, w[18], fmaf(hb2, w[17], fmaf(hb1, w[16], fmaf(hb0, w[15], p3)))));
        float za4 = fmaf(ha4, w[24], fmaf(ha3, w[23], fmaf(ha2, w[22], fmaf(ha1, w[21], fmaf(ha0, w[20], p4)))));
        float zb4 = fmaf(hb4, w[24], fmaf(hb3, w[23], fmaf(hb2, w[22], fmaf(hb1, w[21], fmaf(hb0, w[20], p4)))));
        ha0 = sinrev(za0); hb0 = sinrev(zb0);
        ha1 = sinrev(za1); hb1 = sinrev(zb1);
        ha2 = sinrev(za2); hb2 = sinrev(zb2);
        ha3 = sinrev(za3); hb3 = sinrev(zb3);
        ha4 = sinrev(za4); hb4 = sinrev(zb4);
    }

    // final linear (plain units, no sine)
    float w0 = Wfin[0], w1 = Wfin[1], w2 = Wfin[2], w3 = Wfin[3], w4 = Wfin[4];
    float bb = bfin[0];
    float oa = fmaf(ha4, w4, fmaf(ha3, w3, fmaf(ha2, w2, fmaf(ha1, w1, fmaf(ha0, w0, bb)))));
    float ob = fmaf(hb4, w4, fmaf(hb3, w3, fmaf(hb2, w2, fmaf(hb1, w1, fmaf(hb0, w0, bb)))));

    out[2 * i + 0] = oa;
    out[2 * i + 1] = ob;

    // coords passthrough (second tuple element), 24B contiguous
    float* oc = out + N + 6 * i;
    *(float4*)(oc)     = q0;
    *(float2*)(oc + 4) = q1;
}

extern "C" void kernel_launch(void* const* d_in, const int* in_sizes, int n_in,
                              void* d_out, int out_size, void* d_ws, size_t ws_size,
                              hipStream_t stream) {
    const float* coords = (const float*)d_in[0];
    const float* Wf     = (const float*)d_in[1];
    const float* bf     = (const float*)d_in[2];
    const float* Wh     = (const float*)d_in[3];
    const float* bh     = (const float*)d_in[4];
    const float* Wfin   = (const float*)d_in[5];
    const float* bfin   = (const float*)d_in[6];

    int N = in_sizes[0] / 3;
    float* out = (float*)d_out;
    float* ws = (float*)d_ws;

    hipLaunchKernelGGL(siren_prep, dim3(32), dim3(256), 0, stream, Wf, bf, Wh, bh, ws);

    int M = N / 2;                       // pairs; N=524288 -> 262144 threads
    dim3 block(256);
    dim3 grid((M + 255) / 256);
    hipLaunchKernelGGL(siren_fwd6, grid, block, 0, stream,
                       coords, ws, ws + SIREN_NLAYERS * 32, Wfin, bfin, out, N);
}